// Round 1
// baseline (469.425 us; speedup 1.0000x reference)
//
#include <hip/hip_runtime.h>
#include <hip/hip_bf16.h>

#define GN   50000
#define GE   1600000
#define GIN  32
#define GOUT 32
#define GK   25       // KS^DIM = 25
#define GKO  800      // K * OUT

// ---------------------------------------------------------------------------
// Stage 0: xW[n, k*32+o] = sum_i x[n,i] * W[k,i,o]
// GEMM: [50000 x 32] @ [32 x 800], tiled 64x64, 4x4 register blocking.
// ---------------------------------------------------------------------------
__global__ __launch_bounds__(256) void xw_gemm(const float* __restrict__ X,
                                               const float* __restrict__ W,
                                               float* __restrict__ XW) {
    __shared__ float As[64][33];
    __shared__ float Bs[32][65];
    const int n0  = blockIdx.y * 64;
    const int ko0 = blockIdx.x * 64;
    const int t   = threadIdx.x;

    // Load A tile: 64 rows x 32 cols (float4 = 512 loads, 2 per thread)
    for (int f = t; f < 512; f += 256) {
        int r  = f >> 3;
        int c4 = f & 7;
        int n  = n0 + r;
        float4 v = make_float4(0.f, 0.f, 0.f, 0.f);
        if (n < GN) v = reinterpret_cast<const float4*>(X + (size_t)n * GIN)[c4];
        As[r][c4 * 4 + 0] = v.x;
        As[r][c4 * 4 + 1] = v.y;
        As[r][c4 * 4 + 2] = v.z;
        As[r][c4 * 4 + 3] = v.w;
    }
    // Load B tile: 32 x 64; B(i, ko) = W[(ko>>5)*1024 + i*32 + (ko&31)]
    for (int f = t; f < 2048; f += 256) {
        int i  = f >> 6;
        int j  = f & 63;
        int ko = ko0 + j;
        float v = 0.f;
        if (ko < GKO) {
            int k = ko >> 5, o = ko & 31;
            v = W[k * 1024 + i * 32 + o];
        }
        Bs[i][j] = v;
    }
    __syncthreads();

    const int tx = t & 15, ty = t >> 4;
    float acc[4][4] = {};
#pragma unroll
    for (int k = 0; k < 32; ++k) {
        float a[4], b[4];
#pragma unroll
        for (int m = 0; m < 4; ++m) a[m] = As[ty * 4 + m][k];
#pragma unroll
        for (int j = 0; j < 4; ++j) b[j] = Bs[k][tx * 4 + j];
#pragma unroll
        for (int m = 0; m < 4; ++m)
#pragma unroll
            for (int j = 0; j < 4; ++j) acc[m][j] += a[m] * b[j];
    }

#pragma unroll
    for (int m = 0; m < 4; ++m) {
        int n = n0 + ty * 4 + m;
        if (n >= GN) continue;
#pragma unroll
        for (int j = 0; j < 4; ++j) {
            int ko = ko0 + tx * 4 + j;
            if (ko < GKO) XW[(size_t)n * GKO + ko] = acc[m][j];
        }
    }
}

// ---------------------------------------------------------------------------
// Stage 2: per edge, gather 4 rows of xW (basis-weighted) and scatter-add
// into out[row]. 32 lanes per edge (lane = output channel o).
// Also accumulates in-degree.
// ---------------------------------------------------------------------------
__global__ __launch_bounds__(256) void edge_scatter(const int* __restrict__ ei,
                                                    const float* __restrict__ pseudo,
                                                    const float* __restrict__ xw,
                                                    float* __restrict__ out,
                                                    float* __restrict__ deg) {
    int gid = blockIdx.x * blockDim.x + threadIdx.x;
    int e = gid >> 5;
    int o = gid & 31;
    if (e >= GE) return;

    int row = ei[e];
    int col = ei[GE + e];
    float p0 = pseudo[2 * e];
    float p1 = pseudo[2 * e + 1];

    // degree-1 open B-spline, KS=5: v = p * (5-1)
    float v0 = p0 * 4.0f, v1 = p1 * 4.0f;
    float f0 = floorf(v0), f1 = floorf(v1);
    float fr0 = v0 - f0, fr1 = v1 - f1;
    int i0 = (int)f0, i1 = (int)f1;

    const float* base = xw + (size_t)col * GKO;
    float y = 0.f;
#pragma unroll
    for (int s = 0; s < 4; ++s) {
        float w0 = (s & 1) ? fr0 : 1.f - fr0;
        float w1 = (s & 2) ? fr1 : 1.f - fr1;
        int id0 = (i0 + (s & 1)) % 5;
        int id1 = (i1 + ((s >> 1) & 1)) % 5;
        int wi = id0 + 5 * id1;
        y += (w0 * w1) * base[wi * 32 + o];
    }
    atomicAdd(&out[(size_t)row * 32 + o], y);
    if (o == 0) atomicAdd(&deg[row], 1.0f);
}

// ---------------------------------------------------------------------------
// Fallback (if ws too small): direct per-edge x_e @ W[wi_s], no xW buffer.
// ---------------------------------------------------------------------------
__global__ __launch_bounds__(256) void edge_direct(const int* __restrict__ ei,
                                                   const float* __restrict__ pseudo,
                                                   const float* __restrict__ X,
                                                   const float* __restrict__ W,
                                                   float* __restrict__ out,
                                                   float* __restrict__ deg) {
    int gid = blockIdx.x * blockDim.x + threadIdx.x;
    int e = gid >> 5;
    int o = gid & 31;
    if (e >= GE) return;

    int row = ei[e];
    int col = ei[GE + e];
    float p0 = pseudo[2 * e];
    float p1 = pseudo[2 * e + 1];

    float v0 = p0 * 4.0f, v1 = p1 * 4.0f;
    float f0 = floorf(v0), f1 = floorf(v1);
    float fr0 = v0 - f0, fr1 = v1 - f1;
    int i0 = (int)f0, i1 = (int)f1;

    float xv = X[(size_t)col * 32 + o];
    float y = 0.f;
#pragma unroll
    for (int s = 0; s < 4; ++s) {
        float w0 = (s & 1) ? fr0 : 1.f - fr0;
        float w1 = (s & 2) ? fr1 : 1.f - fr1;
        int id0 = (i0 + (s & 1)) % 5;
        int id1 = (i1 + ((s >> 1) & 1)) % 5;
        int wi = id0 + 5 * id1;
        const float* wb = W + wi * 1024 + o;
        float acc = 0.f;
#pragma unroll
        for (int i = 0; i < 32; ++i) acc += __shfl(xv, i, 32) * wb[i * 32];
        y += (w0 * w1) * acc;
    }
    atomicAdd(&out[(size_t)row * 32 + o], y);
    if (o == 0) atomicAdd(&deg[row], 1.0f);
}

// ---------------------------------------------------------------------------
// Stage 3: out = out/max(deg,1) + x @ root + bias
// ---------------------------------------------------------------------------
__global__ __launch_bounds__(256) void finalize(const float* __restrict__ X,
                                                const float* __restrict__ root,
                                                const float* __restrict__ bias,
                                                const float* __restrict__ deg,
                                                float* __restrict__ out) {
    int t = blockIdx.x * blockDim.x + threadIdx.x;
    if (t >= GN * 32) return;
    int n = t >> 5, o = t & 31;
    float d = fmaxf(deg[n], 1.0f);
    float acc = out[t] / d + bias[o];
    const float* xr = X + (size_t)n * 32;
#pragma unroll
    for (int i = 0; i < 32; ++i) acc += xr[i] * root[i * 32 + o];
    out[t] = acc;
}

extern "C" void kernel_launch(void* const* d_in, const int* in_sizes, int n_in,
                              void* d_out, int out_size, void* d_ws, size_t ws_size,
                              hipStream_t stream) {
    const float* x      = (const float*)d_in[0];
    const int*   ei     = (const int*)d_in[1];
    const float* pseudo = (const float*)d_in[2];
    const float* weight = (const float*)d_in[3];
    const float* root   = (const float*)d_in[4];
    const float* bias   = (const float*)d_in[5];
    float* out = (float*)d_out;

    const size_t xw_bytes  = (size_t)GN * GKO * sizeof(float);  // 160 MB
    const size_t deg_bytes = (size_t)GN * sizeof(float);

    hipMemsetAsync(d_out, 0, (size_t)GN * GOUT * sizeof(float), stream);

    const int edge_blocks = (GE * 32 + 255) / 256;

    if (ws_size >= xw_bytes + deg_bytes) {
        float* xw  = (float*)d_ws;
        float* deg = (float*)((char*)d_ws + xw_bytes);
        hipMemsetAsync(deg, 0, deg_bytes, stream);

        dim3 g0((GKO + 63) / 64, (GN + 63) / 64);
        xw_gemm<<<g0, 256, 0, stream>>>(x, weight, xw);

        edge_scatter<<<edge_blocks, 256, 0, stream>>>(ei, pseudo, xw, out, deg);

        finalize<<<(GN * 32 + 255) / 256, 256, 0, stream>>>(x, root, bias, deg, out);
    } else {
        // ws too small for xW: slow direct path, deg lives at ws start.
        float* deg = (float*)d_ws;
        hipMemsetAsync(deg, 0, deg_bytes, stream);

        edge_direct<<<edge_blocks, 256, 0, stream>>>(ei, pseudo, x, weight, out, deg);

        finalize<<<(GN * 32 + 255) / 256, 256, 0, stream>>>(x, root, bias, deg, out);
    }
}